// Round 2
// baseline (76.963 us; speedup 1.0000x reference)
//
#include <hip/hip_runtime.h>
#include <hip/hip_cooperative_groups.h>
#include <math.h>

namespace cg = cooperative_groups;

#define NROWS 8192
#define DD    64
#define NBLK  256
#define TPB   256
#define WPB   4                       // waves per block
#define RPW   (NROWS / (NBLK * WPB))  // 8 rows per wave

// star-graph GAT, both layers fused. Key identities:
//   e[i][j] = h1[i] + h2[j]; h1[i] cancels in row-softmax -> only s[j]=h[j]·A[:64]
//   row i>0: softmax over {j=0, j=i} (others underflow to exact 0) -> 2-way softmax
//   row 0:   full softmax over all j -> global weighted sum (partials + combine)
__global__ __launch_bounds__(TPB, 1) void gat_fused(
    const float* __restrict__ x, const float* __restrict__ A1,
    const float* __restrict__ A2, float* __restrict__ out,
    float* __restrict__ part1, float* __restrict__ z1,
    float* __restrict__ part2, float* __restrict__ z2)
{
    cg::grid_group grid = cg::this_grid();
    const int lane = threadIdx.x & 63;
    const int wl   = threadIdx.x >> 6;
    const int blk  = blockIdx.x;
    const int row0 = (blk * WPB + wl) * RPW;

    __shared__ float sacc[WPB][DD];
    __shared__ float sz[WPB];

    // ---------------- layer 1: rows + partials ----------------
    float w1 = A1[lane];              // only A[:d] matters
    float h0 = x[lane];               // x row 0 (lane-distributed)
    float v0 = h0 * w1;
    #pragma unroll
    for (int o = 32; o; o >>= 1) v0 += __shfl_xor(v0, o);
    float e0 = expf(v0);              // exp(s0), no max-sub needed (|s|<~5)

    float acc = 0.f, z = 0.f;
    #pragma unroll
    for (int k = 0; k < RPW; ++k) {
        int r = row0 + k;
        float hv = x[r * DD + lane];
        float t = hv * w1;
        #pragma unroll
        for (int o = 32; o; o >>= 1) t += __shfl_xor(t, o);
        float e = expf(t);
        acc += e * hv;                // row-0 weighted-sum partial
        z   += e;
        if (r != 0) {                 // 2-way softmax: {row 0, row r}
            float inv = 1.f / (e0 + e);
            out[r * DD + lane] = (e0 * h0 + e * hv) * inv;
        }
    }
    sacc[wl][lane] = acc;
    if (lane == 0) sz[wl] = z;
    __syncthreads();
    if (wl == 0) {
        part1[blk * DD + lane] = sacc[0][lane] + sacc[1][lane] + sacc[2][lane] + sacc[3][lane];
        if (lane == 0) z1[blk] = sz[0] + sz[1] + sz[2] + sz[3];
    }

    grid.sync();

    // ------- redundant combine of layer-1 row 0 (every block, fixed order) -------
    float a = 0.f;
    #pragma unroll 8
    for (int b = wl * 64; b < wl * 64 + 64; ++b) a += part1[b * DD + lane];
    float zz = z1[wl * 64 + lane];
    #pragma unroll
    for (int o = 32; o; o >>= 1) zz += __shfl_xor(zz, o);
    sacc[wl][lane] = a;
    if (lane == 0) sz[wl] = zz;
    __syncthreads();
    float atot = sacc[0][lane] + sacc[1][lane] + sacc[2][lane] + sacc[3][lane];
    float Z    = sz[0] + sz[1] + sz[2] + sz[3];
    float h0_2 = atot / Z;            // layer-1 out[0], lane-distributed, never stored

    // ---------------- layer 2 (in-place on out): rows + partials ----------------
    float w2 = A2[lane];
    float t0 = h0_2 * w2;
    #pragma unroll
    for (int o = 32; o; o >>= 1) t0 += __shfl_xor(t0, o);
    float e0_2 = expf(t0);

    acc = 0.f; z = 0.f;
    #pragma unroll
    for (int k = 0; k < RPW; ++k) {
        int r = row0 + k;
        float hv = (r == 0) ? h0_2 : out[r * DD + lane];  // own row only -> no race
        float t = hv * w2;
        #pragma unroll
        for (int o = 32; o; o >>= 1) t += __shfl_xor(t, o);
        float e = expf(t);
        acc += e * hv;
        z   += e;
        if (r != 0) {
            float inv = 1.f / (e0_2 + e);
            out[r * DD + lane] = (e0_2 * h0_2 + e * hv) * inv;
        }
    }
    __syncthreads();                  // protect sacc reads above before rewrite
    sacc[wl][lane] = acc;
    if (lane == 0) sz[wl] = z;
    __syncthreads();
    if (wl == 0) {
        part2[blk * DD + lane] = sacc[0][lane] + sacc[1][lane] + sacc[2][lane] + sacc[3][lane];
        if (lane == 0) z2[blk] = sz[0] + sz[1] + sz[2] + sz[3];
    }

    grid.sync();

    // ---------------- final layer-2 row 0 (block 0 only) ----------------
    if (blk == 0) {
        float a2 = 0.f;
        #pragma unroll 8
        for (int b = wl * 64; b < wl * 64 + 64; ++b) a2 += part2[b * DD + lane];
        float zz2 = z2[wl * 64 + lane];
        #pragma unroll
        for (int o = 32; o; o >>= 1) zz2 += __shfl_xor(zz2, o);
        sacc[wl][lane] = a2;
        if (lane == 0) sz[wl] = zz2;
        __syncthreads();
        if (wl == 0) {
            float at2 = sacc[0][lane] + sacc[1][lane] + sacc[2][lane] + sacc[3][lane];
            float Z2  = sz[0] + sz[1] + sz[2] + sz[3];
            out[lane] = at2 / Z2;
        }
    }
}

extern "C" void kernel_launch(void* const* d_in, const int* in_sizes, int n_in,
                              void* d_out, int out_size, void* d_ws, size_t ws_size,
                              hipStream_t stream)
{
    const float* x  = (const float*)d_in[0];
    const float* A1 = (const float*)d_in[1];
    const float* A2 = (const float*)d_in[2];
    float* out = (float*)d_out;
    float* ws  = (float*)d_ws;

    float* part1 = ws;                    // 256*64
    float* z1    = ws + NBLK * DD;        // 256
    float* part2 = z1 + NBLK;             // 256*64
    float* z2    = part2 + NBLK * DD;     // 256

    void* args[] = { (void*)&x, (void*)&A1, (void*)&A2, (void*)&out,
                     (void*)&part1, (void*)&z1, (void*)&part2, (void*)&z2 };
    hipLaunchCooperativeKernel((const void*)gat_fused, dim3(NBLK), dim3(TPB),
                               args, 0, stream);
}

// Round 3
// 44.741 us; speedup vs baseline: 1.7202x; 1.7202x over previous
//
#include <hip/hip_runtime.h>
#include <math.h>

#define NROWS 8192
#define DD    64
#define LBLK  512
#define TPB   256
#define WPB   4                        // waves per block
#define RPW   (NROWS / (LBLK * WPB))   // 4 rows per wave

// One GAT layer on the star graph. Identities (validated rounds 1-2):
//   e[i][j] = h1[i] + h2[j]; h1 cancels in the row softmax -> only s[j]=h[j]·A[:64]
//   row i>0: masked softmax reduces to 2-way between {j=0, j=i} (rest underflow to 0)
//   row 0:   full softmax -> global weighted sum, done via per-block partials +
//            last-block fixed-order combine (deterministic).
// exp without max-subtraction is safe: |s| <~ 8 in fp32 (validated, absmax 4e-3).
__global__ __launch_bounds__(TPB) void gat_layer_k(
    const float* __restrict__ h_in, const float* __restrict__ A,
    float* __restrict__ h_out, float* __restrict__ partials,
    float* __restrict__ zpart, unsigned int* __restrict__ counter)
{
    const int lane = threadIdx.x & 63;
    const int wl   = threadIdx.x >> 6;
    const int r0   = (blockIdx.x * WPB + wl) * RPW;

    __shared__ float sacc[WPB][DD];
    __shared__ float sz[WPB];
    __shared__ int amLast;

    float w  = A[lane];                 // only A[:d]; A[d:] cancels
    float h0 = h_in[lane];              // row 0, lane-distributed (read BEFORE counter++)
    float v0 = h0 * w;
    #pragma unroll
    for (int o = 32; o; o >>= 1) v0 += __shfl_xor(v0, o);
    float e0 = expf(v0);

    float acc = 0.f, z = 0.f;
    #pragma unroll
    for (int k = 0; k < RPW; ++k) {
        int r = r0 + k;
        float hv = h_in[r * DD + lane]; // own row only -> in-place safe
        float t = hv * w;
        #pragma unroll
        for (int o = 32; o; o >>= 1) t += __shfl_xor(t, o);
        float e = expf(t);
        acc += e * hv;                  // row-0 weighted-sum partial
        z   += e;
        if (r != 0) {                   // 2-way softmax {row 0, row r}
            float inv = 1.f / (e0 + e);
            h_out[r * DD + lane] = (e0 * h0 + e * hv) * inv;
        }
    }

    // block-level partial reduce
    sacc[wl][lane] = acc;
    if (lane == 0) sz[wl] = z;
    __syncthreads();
    if (wl == 0) {
        partials[blockIdx.x * DD + lane] =
            sacc[0][lane] + sacc[1][lane] + sacc[2][lane] + sacc[3][lane];
        if (lane == 0) zpart[blockIdx.x] = sz[0] + sz[1] + sz[2] + sz[3];
    }
    __syncthreads();                    // all waves' global writes issued + drained

    // last-block-done (rocPRIM pattern): release-fence, count, last block combines
    if (threadIdx.x == 0) {
        __threadfence();
        unsigned old = atomicAdd(counter, 1u);
        amLast = (old == LBLK - 1) ? 1 : 0;
    }
    __syncthreads();

    if (amLast) {
        __threadfence();                // acquire: invalidate stale cache lines
        float a = 0.f;
        const int chunk = LBLK / WPB;   // 128 partials per wave, fixed order
        for (int b = wl * chunk; b < (wl + 1) * chunk; ++b)
            a += partials[b * DD + lane];
        sacc[wl][lane] = a;
        __syncthreads();
        if (wl == 0) {
            float at = sacc[0][lane] + sacc[1][lane] + sacc[2][lane] + sacc[3][lane];
            float zz = 0.f;
            #pragma unroll
            for (int b = 0; b < LBLK / DD; ++b) zz += zpart[b * DD + lane];
            #pragma unroll
            for (int o = 32; o; o >>= 1) zz += __shfl_xor(zz, o);
            h_out[lane] = at / zz;      // row 0: written after ALL blocks read h_in[0]
        }
    }
}

extern "C" void kernel_launch(void* const* d_in, const int* in_sizes, int n_in,
                              void* d_out, int out_size, void* d_ws, size_t ws_size,
                              hipStream_t stream)
{
    const float* x  = (const float*)d_in[0];
    const float* A1 = (const float*)d_in[1];
    const float* A2 = (const float*)d_in[2];
    float* out = (float*)d_out;
    float* ws  = (float*)d_ws;

    float* partials        = ws;                         // 512*64 floats
    float* zpart           = ws + LBLK * DD;             // 512 floats
    unsigned int* counters = (unsigned int*)(zpart + LBLK); // 2 uints

    hipMemsetAsync(counters, 0, 2 * sizeof(unsigned int), stream);

    gat_layer_k<<<LBLK, TPB, 0, stream>>>(x,   A1, out, partials, zpart, counters + 0);
    gat_layer_k<<<LBLK, TPB, 0, stream>>>(out, A2, out, partials, zpart, counters + 1);
}

// Round 4
// 31.341 us; speedup vs baseline: 2.4557x; 1.4276x over previous
//
#include <hip/hip_runtime.h>
#include <math.h>

#define NROWS 8192
#define DD    64
#define LBLK  512
#define TPB   256
#define WPB   4                        // waves per block
#define RPW   (NROWS / (LBLK * WPB))   // 4 rows per wave
#define CHUNK (LBLK / WPB)             // 128 partials combined per wave

// Star-graph GAT identities (validated rounds 1-3, absmax 3.9e-3):
//   e[i][j] = h1[i] + h2[j]; h1 cancels in row softmax -> only s[j] = h[j]·A[:64]
//   row i>0: masked softmax = 2-way between {j=0, j=i} (rest underflow to exact 0)
//   row 0:   full softmax -> per-block partials + fixed-order combine
//   exp without max-subtraction safe in fp32 (|s| <~ 8)

// K1: layer-1 rows>0 (needs only redundant e0 from x row 0) + row-0 partials.
// Also zeros K2's counter (no hipMemsetAsync node - it cost 38.7us/replay).
__global__ __launch_bounds__(TPB) void gat_l1_k(
    const float* __restrict__ x, const float* __restrict__ A1,
    float* __restrict__ out, float* __restrict__ part1, float* __restrict__ z1,
    unsigned int* __restrict__ counter)
{
    if (blockIdx.x == 0 && threadIdx.x == 0) *counter = 0u;

    const int lane = threadIdx.x & 63;
    const int wl   = threadIdx.x >> 6;
    const int r0   = (blockIdx.x * WPB + wl) * RPW;

    __shared__ float sacc[WPB][DD];
    __shared__ float sz[WPB];

    float w  = A1[lane];
    float x0 = x[lane];                  // row 0, lane-distributed
    float v0 = x0 * w;
    #pragma unroll
    for (int o = 32; o; o >>= 1) v0 += __shfl_xor(v0, o);
    float e0 = expf(v0);

    float acc = 0.f, z = 0.f;
    #pragma unroll
    for (int k = 0; k < RPW; ++k) {
        int r = r0 + k;
        float hv = x[r * DD + lane];
        float t = hv * w;
        #pragma unroll
        for (int o = 32; o; o >>= 1) t += __shfl_xor(t, o);
        float e = expf(t);
        acc += e * hv;                   // row-0 weighted-sum partial (includes r=0)
        z   += e;
        if (r != 0) {                    // 2-way softmax {0, r}
            float inv = 1.f / (e0 + e);
            out[r * DD + lane] = (e0 * x0 + e * hv) * inv;
        }
    }
    sacc[wl][lane] = acc;
    if (lane == 0) sz[wl] = z;
    __syncthreads();
    if (wl == 0) {
        part1[blockIdx.x * DD + lane] =
            sacc[0][lane] + sacc[1][lane] + sacc[2][lane] + sacc[3][lane];
        if (lane == 0) z1[blockIdx.x] = sz[0] + sz[1] + sz[2] + sz[3];
    }
}

// K2: every block redundantly combines layer-1 partials (fixed order) -> h1_0;
// layer-2 rows>0 in-place; layer-2 partials; last-block writes out[0].
__global__ __launch_bounds__(TPB) void gat_l2_k(
    const float* __restrict__ A2, float* __restrict__ out,
    const float* __restrict__ part1, const float* __restrict__ z1,
    float* __restrict__ part2, float* __restrict__ z2,
    unsigned int* __restrict__ counter)
{
    const int lane = threadIdx.x & 63;
    const int wl   = threadIdx.x >> 6;
    const int r0   = (blockIdx.x * WPB + wl) * RPW;

    __shared__ float sacc[WPB][DD];
    __shared__ float sz[WPB];
    __shared__ int amLast;

    // ---- redundant combine of layer-1 row 0 (identical fixed order per block) ----
    float a = 0.f;
    for (int b = wl * CHUNK; b < (wl + 1) * CHUNK; ++b)
        a += part1[b * DD + lane];
    float zz = z1[wl * CHUNK + lane] + z1[wl * CHUNK + DD + lane];  // CHUNK = 2*DD
    #pragma unroll
    for (int o = 32; o; o >>= 1) zz += __shfl_xor(zz, o);
    sacc[wl][lane] = a;
    if (lane == 0) sz[wl] = zz;
    __syncthreads();
    float P  = sacc[0][lane] + sacc[1][lane] + sacc[2][lane] + sacc[3][lane];
    float Z  = sz[0] + sz[1] + sz[2] + sz[3];
    float h0 = P / Z;                    // layer-1 out[0], never stored to memory

    // ---- layer 2 main (in place on out; each wave touches only its own rows) ----
    float w  = A2[lane];
    float v0 = h0 * w;
    #pragma unroll
    for (int o = 32; o; o >>= 1) v0 += __shfl_xor(v0, o);
    float e0 = expf(v0);

    float acc = 0.f, z = 0.f;
    #pragma unroll
    for (int k = 0; k < RPW; ++k) {
        int r = r0 + k;
        float hv = (r == 0) ? h0 : out[r * DD + lane];
        float t = hv * w;
        #pragma unroll
        for (int o = 32; o; o >>= 1) t += __shfl_xor(t, o);
        float e = expf(t);
        acc += e * hv;
        z   += e;
        if (r != 0) {
            float inv = 1.f / (e0 + e);
            out[r * DD + lane] = (e0 * h0 + e * hv) * inv;
        }
    }
    __syncthreads();                     // sacc/sz reads above done before rewrite
    sacc[wl][lane] = acc;
    if (lane == 0) sz[wl] = z;
    __syncthreads();
    if (wl == 0) {
        part2[blockIdx.x * DD + lane] =
            sacc[0][lane] + sacc[1][lane] + sacc[2][lane] + sacc[3][lane];
        if (lane == 0) z2[blockIdx.x] = sz[0] + sz[1] + sz[2] + sz[3];
    }
    __syncthreads();

    // ---- last-block-done: counter was zeroed by K1 ----
    if (threadIdx.x == 0) {
        __threadfence();                 // release: partials visible device-wide
        unsigned old = atomicAdd(counter, 1u);
        amLast = (old == LBLK - 1) ? 1 : 0;
    }
    __syncthreads();

    if (amLast) {
        __threadfence();                 // acquire
        float a2 = 0.f;
        for (int b = wl * CHUNK; b < (wl + 1) * CHUNK; ++b)
            a2 += part2[b * DD + lane];
        float zz2 = z2[wl * CHUNK + lane] + z2[wl * CHUNK + DD + lane];
        #pragma unroll
        for (int o = 32; o; o >>= 1) zz2 += __shfl_xor(zz2, o);
        sacc[wl][lane] = a2;
        if (lane == 0) sz[wl] = zz2;
        __syncthreads();
        if (wl == 0) {
            float P2 = sacc[0][lane] + sacc[1][lane] + sacc[2][lane] + sacc[3][lane];
            float Z2 = sz[0] + sz[1] + sz[2] + sz[3];
            out[lane] = P2 / Z2;         // fixed-order -> deterministic
        }
    }
}

extern "C" void kernel_launch(void* const* d_in, const int* in_sizes, int n_in,
                              void* d_out, int out_size, void* d_ws, size_t ws_size,
                              hipStream_t stream)
{
    const float* x  = (const float*)d_in[0];
    const float* A1 = (const float*)d_in[1];
    const float* A2 = (const float*)d_in[2];
    float* out = (float*)d_out;
    float* ws  = (float*)d_ws;

    float* part1 = ws;                        // 512*64
    float* z1    = part1 + LBLK * DD;         // 512
    float* part2 = z1 + LBLK;                 // 512*64
    float* z2    = part2 + LBLK * DD;         // 512
    unsigned int* counter = (unsigned int*)(z2 + LBLK);

    gat_l1_k<<<LBLK, TPB, 0, stream>>>(x, A1, out, part1, z1, counter);
    gat_l2_k<<<LBLK, TPB, 0, stream>>>(A2, out, part1, z1, part2, z2, counter);
}

// Round 5
// 21.641 us; speedup vs baseline: 3.5564x; 1.4482x over previous
//
#include <hip/hip_runtime.h>
#include <math.h>

#define NROWS 8192
#define DD    64
#define LBLK  256                      // blocks per layer kernel
#define TPB   512                      // 8 waves/block
#define WPB   8
#define RPW   (NROWS / (LBLK * WPB))   // 4 rows per wave
#define CHUNK (LBLK / WPB)             // 32 partials combined per wave

// Star-graph GAT identities (validated rounds 1-4, absmax 3.9e-3):
//   e[i][j] = h1[i] + h2[j]; h1 cancels in row softmax -> only s[j] = h[j]·A[:64]
//   row i>0: masked softmax = 2-way between {j=0, j=i} (rest underflow to exact 0)
//   row 0:   full softmax -> per-block partials + fixed-order combine
//   exp without max-subtraction safe in fp32 (|s| <~ 8)
// Counter protocol (poison-proof): K1 zeroes K2's counter with a plain store;
// kernel-boundary ordering guarantees visibility before any K2 atomic. No
// memset node (cost ~13 us/replay), no cross-replay state assumptions.

__global__ __launch_bounds__(TPB) void gat_l1_k(
    const float* __restrict__ x, const float* __restrict__ A1,
    float* __restrict__ out, float* __restrict__ part1, float* __restrict__ z1,
    unsigned int* __restrict__ counter)
{
    if (blockIdx.x == 0 && threadIdx.x == 0) *counter = 0u;

    const int lane = threadIdx.x & 63;
    const int wl   = threadIdx.x >> 6;
    const int r0   = (blockIdx.x * WPB + wl) * RPW;

    __shared__ float sacc[WPB][DD];
    __shared__ float sz[WPB];

    float w  = A1[lane];
    float x0 = x[lane];                  // row 0, lane-distributed
    float v0 = x0 * w;
    #pragma unroll
    for (int o = 32; o; o >>= 1) v0 += __shfl_xor(v0, o);
    float e0 = expf(v0);

    float acc = 0.f, z = 0.f;
    #pragma unroll
    for (int k = 0; k < RPW; ++k) {
        int r = r0 + k;
        float hv = x[r * DD + lane];
        float t = hv * w;
        #pragma unroll
        for (int o = 32; o; o >>= 1) t += __shfl_xor(t, o);
        float e = expf(t);
        acc += e * hv;                   // row-0 weighted-sum partial (incl. r=0)
        z   += e;
        if (r != 0) {                    // 2-way softmax {0, r}
            float inv = 1.f / (e0 + e);
            out[r * DD + lane] = (e0 * x0 + e * hv) * inv;
        }
    }
    sacc[wl][lane] = acc;
    if (lane == 0) sz[wl] = z;
    __syncthreads();
    if (wl == 0) {
        float p = 0.f;
        #pragma unroll
        for (int j = 0; j < WPB; ++j) p += sacc[j][lane];
        part1[blockIdx.x * DD + lane] = p;
        if (lane == 0) {
            float zs = 0.f;
            #pragma unroll
            for (int j = 0; j < WPB; ++j) zs += sz[j];
            z1[blockIdx.x] = zs;
        }
    }
}

__global__ __launch_bounds__(TPB) void gat_l2_k(
    const float* __restrict__ A2, float* __restrict__ out,
    const float* __restrict__ part1, const float* __restrict__ z1,
    float* __restrict__ part2, float* __restrict__ z2,
    unsigned int* __restrict__ counter)
{
    const int lane = threadIdx.x & 63;
    const int wl   = threadIdx.x >> 6;
    const int r0   = (blockIdx.x * WPB + wl) * RPW;

    __shared__ float sacc[WPB][DD];
    __shared__ float sz[WPB];
    __shared__ int amLast;

    // Pre-load this wave's rows so their latency hides under the combine.
    // (out[0] read here is stale/poison; replaced by h0 below.)
    float hvr[RPW];
    #pragma unroll
    for (int k = 0; k < RPW; ++k) hvr[k] = out[(r0 + k) * DD + lane];

    // ---- redundant combine of layer-1 row 0 (fixed order, fully unrolled) ----
    float a = 0.f;
    #pragma unroll
    for (int i = 0; i < CHUNK; ++i) a += part1[(wl * CHUNK + i) * DD + lane];
    float zz = (lane < CHUNK) ? z1[wl * CHUNK + lane] : 0.f;
    #pragma unroll
    for (int o = 32; o; o >>= 1) zz += __shfl_xor(zz, o);
    sacc[wl][lane] = a;
    if (lane == 0) sz[wl] = zz;
    __syncthreads();
    float P = 0.f, Z = 0.f;
    #pragma unroll
    for (int j = 0; j < WPB; ++j) P += sacc[j][lane];
    #pragma unroll
    for (int j = 0; j < WPB; ++j) Z += sz[j];
    float h0 = P / Z;                    // layer-1 out[0], never stored to memory

    // ---- layer 2 main (in place; each wave owns its rows) ----
    float w  = A2[lane];
    float v0 = h0 * w;
    #pragma unroll
    for (int o = 32; o; o >>= 1) v0 += __shfl_xor(v0, o);
    float e0 = expf(v0);

    float acc = 0.f, z = 0.f;
    #pragma unroll
    for (int k = 0; k < RPW; ++k) {
        int r = r0 + k;
        float hv = (r == 0) ? h0 : hvr[k];
        float t = hv * w;
        #pragma unroll
        for (int o = 32; o; o >>= 1) t += __shfl_xor(t, o);
        float e = expf(t);
        acc += e * hv;
        z   += e;
        if (r != 0) {
            float inv = 1.f / (e0 + e);
            out[r * DD + lane] = (e0 * h0 + e * hv) * inv;
        }
    }
    __syncthreads();                     // sacc/sz combine-reads done before rewrite
    sacc[wl][lane] = acc;
    if (lane == 0) sz[wl] = z;
    __syncthreads();
    if (wl == 0) {
        float p = 0.f;
        #pragma unroll
        for (int j = 0; j < WPB; ++j) p += sacc[j][lane];
        part2[blockIdx.x * DD + lane] = p;
        if (lane == 0) {
            float zs = 0.f;
            #pragma unroll
            for (int j = 0; j < WPB; ++j) zs += sz[j];
            z2[blockIdx.x] = zs;
        }
    }
    __syncthreads();                     // all waves' global writes issued + drained

    // ---- last-block-done: counter zeroed by K1 (cross-kernel ordering) ----
    if (threadIdx.x == 0) {
        __threadfence();                 // release
        unsigned old = atomicAdd(counter, 1u);
        amLast = (old == LBLK - 1) ? 1 : 0;
    }
    __syncthreads();

    if (amLast) {
        __threadfence();                 // acquire
        float a2 = 0.f;
        #pragma unroll
        for (int i = 0; i < CHUNK; ++i) a2 += part2[(wl * CHUNK + i) * DD + lane];
        float zz2 = (lane < CHUNK) ? z2[wl * CHUNK + lane] : 0.f;
        #pragma unroll
        for (int o = 32; o; o >>= 1) zz2 += __shfl_xor(zz2, o);
        sacc[wl][lane] = a2;
        if (lane == 0) sz[wl] = zz2;
        __syncthreads();
        if (wl == 0) {
            float P2 = 0.f, Z2 = 0.f;
            #pragma unroll
            for (int j = 0; j < WPB; ++j) P2 += sacc[j][lane];
            #pragma unroll
            for (int j = 0; j < WPB; ++j) Z2 += sz[j];
            out[lane] = P2 / Z2;         // fixed order -> deterministic
        }
    }
}

extern "C" void kernel_launch(void* const* d_in, const int* in_sizes, int n_in,
                              void* d_out, int out_size, void* d_ws, size_t ws_size,
                              hipStream_t stream)
{
    const float* x  = (const float*)d_in[0];
    const float* A1 = (const float*)d_in[1];
    const float* A2 = (const float*)d_in[2];
    float* out = (float*)d_out;
    float* ws  = (float*)d_ws;

    float* part1 = ws;                        // 256*64
    float* z1    = part1 + LBLK * DD;         // 256
    float* part2 = z1 + LBLK;                 // 256*64
    float* z2    = part2 + LBLK * DD;         // 256
    unsigned int* counter = (unsigned int*)(z2 + LBLK);

    gat_l1_k<<<LBLK, TPB, 0, stream>>>(x, A1, out, part1, z1, counter);
    gat_l2_k<<<LBLK, TPB, 0, stream>>>(A2, out, part1, z1, part2, z2, counter);
}